// Round 2
// baseline (892.207 us; speedup 1.0000x reference)
//
#include <hip/hip_runtime.h>

// EntNet: B=32, S=256, L=64, D=100, M=20
// K1 encode_k : one row/block contiguous streaming -> LDS stage -> column reduce
// K0 prep_k   : T[d][e] = W[e][d] / keys
// K2 project_k: sWp = enc·W^T, kg = enc·keys^T via T
// K3 entnet_scan: latency-bound serial recurrence -> run TWO m-chains per wave
//    (same b: U regs + enc/sWp loads shared). One chain's stalls are filled by
//    the other chain's issue. 320 blocks, 1 wave each, LDS cand broadcast +
//    v_pk_fma_f32 packed matvec.

typedef float v2f __attribute__((ext_vector_type(2)));

__global__ __launch_bounds__(320) void encode_k(
    const float* __restrict__ batch,
    const float* __restrict__ encm,
    float* __restrict__ enc)
{
    __shared__ float prod[6400];
    __shared__ float part[200];
    const int t = threadIdx.x;
    const int row = blockIdx.x;       // 8192 blocks
    const float4* rb = (const float4*)batch + (size_t)row * 1600;
    const float4* e4 = (const float4*)encm;
    float4* p4 = (float4*)prod;
    #pragma unroll
    for (int i = 0; i < 5; ++i) {
        const int idx = i * 320 + t;
        float4 x = rb[idx];
        float4 mu = e4[idx];
        float4 p;
        p.x = x.x * mu.x; p.y = x.y * mu.y; p.z = x.z * mu.z; p.w = x.w * mu.w;
        p4[idx] = p;
    }
    __syncthreads();
    if (t < 200) {
        const int c = (t < 100) ? t : (t - 100);
        const int l0 = (t < 100) ? 0 : 32;
        float s0 = 0.f, s1 = 0.f;
        #pragma unroll
        for (int l = 0; l < 32; l += 2) {
            s0 += prod[(l0 + l) * 100 + c];
            s1 += prod[(l0 + l + 1) * 100 + c];
        }
        part[t] = s0 + s1;
    }
    __syncthreads();
    if (t < 100) enc[(size_t)row * 100 + t] = part[t] + part[100 + t];
}

__global__ void prep_k(const float* __restrict__ W,
                       const float* __restrict__ keys,
                       float* __restrict__ T)
{
    const int d = blockIdx.x;
    const int e = threadIdx.x;
    float v = 0.f;
    if (e < 100) v = W[e * 100 + d];
    else if (e < 120) v = keys[(e - 100) * 100 + d];
    T[d * 128 + e] = v;
}

__global__ __launch_bounds__(128) void project_k(
    const float* __restrict__ enc,
    const float* __restrict__ T,
    float* __restrict__ sWp,
    float* __restrict__ kg)
{
    __shared__ float encS[400];
    const int t = threadIdx.x;
    const int row0 = blockIdx.x * 4;
    if (t < 100) ((float4*)encS)[t] = ((const float4*)(enc + (size_t)row0 * 100))[t];
    __syncthreads();
    float a0 = 0.f, a1 = 0.f, a2 = 0.f, a3 = 0.f;
    #pragma unroll 4
    for (int d = 0; d < 100; ++d) {
        const float w = T[d * 128 + t];
        a0 += w * encS[d];
        a1 += w * encS[100 + d];
        a2 += w * encS[200 + d];
        a3 += w * encS[300 + d];
    }
    if (t < 100) {
        sWp[(size_t)row0 * 100 + t]       = a0;
        sWp[(size_t)(row0 + 1) * 100 + t] = a1;
        sWp[(size_t)(row0 + 2) * 100 + t] = a2;
        sWp[(size_t)(row0 + 3) * 100 + t] = a3;
    } else if (t < 120) {
        const int m = t - 100;
        kg[(size_t)row0 * 20 + m]       = a0;
        kg[(size_t)(row0 + 1) * 20 + m] = a1;
        kg[(size_t)(row0 + 2) * 20 + m] = a2;
        kg[(size_t)(row0 + 3) * 20 + m] = a3;
    }
}

template <int CTRL>
__device__ __forceinline__ float dpp_add_f(float x) {
    int s = __builtin_amdgcn_update_dpp(0, __float_as_int(x), CTRL, 0xF, 0xF, true);
    return x + __int_as_float(s);
}
__device__ __forceinline__ float lane63(float x) {
    return __int_as_float(__builtin_amdgcn_readlane(__float_as_int(x), 63));
}
#define DPP6(v) v = dpp_add_f<0x111>(v); v = dpp_add_f<0x112>(v); v = dpp_add_f<0x114>(v); \
                v = dpp_add_f<0x118>(v); v = dpp_add_f<0x142>(v); v = dpp_add_f<0x143>(v);

// Dual-chain matvec: RA = U . candA, RB = U . candB (candX broadcast from LDS).
// 50 uniform ds_read_b128 + 200 v_pk_fma_f32 in 8 independent accumulator
// chains; A/B interleaved per-j so either chain's fmas fill the other's waits.
#define MATVEC2(RA, RB)                                                 \
    {                                                                   \
        v2f A0 = {0.f,0.f}, A1 = {0.f,0.f}, A2 = {0.f,0.f}, A3 = {0.f,0.f}; \
        v2f B0 = {0.f,0.f}, B1 = {0.f,0.f}, B2 = {0.f,0.f}, B3 = {0.f,0.f}; \
        _Pragma("unroll")                                               \
        for (int j = 0; j < 25; ++j) {                                  \
            float4 ca = cbufA4[j];                                      \
            float4 cb = cbufB4[j];                                      \
            v2f calo = {ca.x, ca.y}, cahi = {ca.z, ca.w};               \
            v2f cblo = {cb.x, cb.y}, cbhi = {cb.z, cb.w};               \
            A0 = __builtin_elementwise_fma(UE0[2 * j],     calo, A0);   \
            A1 = __builtin_elementwise_fma(UE0[2 * j + 1], cahi, A1);   \
            A2 = __builtin_elementwise_fma(UE1[2 * j],     calo, A2);   \
            A3 = __builtin_elementwise_fma(UE1[2 * j + 1], cahi, A3);   \
            B0 = __builtin_elementwise_fma(UE0[2 * j],     cblo, B0);   \
            B1 = __builtin_elementwise_fma(UE0[2 * j + 1], cbhi, B1);   \
            B2 = __builtin_elementwise_fma(UE1[2 * j],     cblo, B2);   \
            B3 = __builtin_elementwise_fma(UE1[2 * j + 1], cbhi, B3);   \
        }                                                               \
        v2f sA = A0 + A1, sB = A2 + A3;                                 \
        RA.x = sA.x + sA.y;  RA.y = sB.x + sB.y;                        \
        v2f tA = B0 + B1, tB = B2 + B3;                                 \
        RB.x = tA.x + tA.y;  RB.y = tB.x + tB.y;                        \
    }

__global__ __attribute__((amdgpu_waves_per_eu(1, 1))) __launch_bounds__(64)
void entnet_scan(
    const float* __restrict__ enc,    // [8192*100]
    const float* __restrict__ sWp,    // [8192*100]
    const float* __restrict__ kg,     // [8192*20]
    const float* __restrict__ keys,   // [20*100]
    const float* __restrict__ U,      // [100*100]
    const float* __restrict__ V,      // [100*100]
    const float* __restrict__ paPtr,
    float* __restrict__ out)          // [32*20*100]
{
    __shared__ float4 cbufA4[32];     // chain A cand broadcast (128 floats)
    __shared__ float4 cbufB4[32];     // chain B
    float* cbufA = (float*)cbufA4;
    float* cbufB = (float*)cbufB4;
    const int lane = threadIdx.x;
    // 320 blocks: XCD = blockIdx%8 serves b in {4*xcd..4*xcd+3}; chains (b,mp),(b,mp+10)
    const int xcd = blockIdx.x & 7;
    const int gg  = blockIdx.x >> 3;          // 0..39
    const int b  = xcd * 4 + gg / 10;
    const int mA = gg % 10;
    const int mB = mA + 10;
    const bool hi = (lane < 36);
    const float h = hi ? 1.f : 0.f;
    const int e0 = lane;
    const int e1 = hi ? (64 + lane) : 99;
    const float pa = paPtr[0];

    // U rows e0/e1 as (k,k+1) v2f pairs, shared by both chains.
    v2f UE0[50], UE1[50];
    {
        const float4* u0 = (const float4*)(U + e0 * 100);
        const float4* u1 = (const float4*)(U + e1 * 100);
        #pragma unroll
        for (int k = 0; k < 25; ++k) {
            float4 a = u0[k], c = u1[k];
            UE0[2 * k]     = (v2f){a.x, a.y};
            UE0[2 * k + 1] = (v2f){a.z, a.w};
            UE1[2 * k]     = (v2f){c.x, c.y};
            UE1[2 * k + 1] = (v2f){c.z, c.w};
        }
    }

    // kv = V[e,:] . keys[m,:] for both chains (V row loads shared)
    float kvA0 = 0.f, kvA1 = 0.f, kvB0 = 0.f, kvB1 = 0.f;
    {
        const float4* kmA = (const float4*)(keys + mA * 100);
        const float4* kmB = (const float4*)(keys + mB * 100);
        const float4* v0 = (const float4*)(V + e0 * 100);
        const float4* v1 = (const float4*)(V + e1 * 100);
        #pragma unroll
        for (int k = 0; k < 25; ++k) {
            float4 a = v0[k], c = v1[k], ka = kmA[k], kb = kmB[k];
            kvA0 += a.x * ka.x + a.y * ka.y + a.z * ka.z + a.w * ka.w;
            kvA1 += c.x * ka.x + c.y * ka.y + c.z * ka.z + c.w * ka.w;
            kvB0 += a.x * kb.x + a.y * kb.y + a.z * kb.z + a.w * kb.w;
            kvB1 += c.x * kb.x + c.y * kb.y + c.z * kb.z + c.w * kb.w;
        }
    }
    const float k0A = keys[mA * 100 + e0];
    const float k1A = h * keys[mA * 100 + e1];
    const float k0B = keys[mB * 100 + e0];
    const float k1B = h * keys[mB * 100 + e1];
    float nmA0 = k0A, nmA1 = k1A;     // unnormalized mem; true mem = rn*nm
    float nmB0 = k0B, nmB1 = k1B;

    v2f PA, PB;                       // P = U . nm (register recurrence)
    cbufA[lane] = k0A; cbufA[64 + lane] = k1A;
    cbufB[lane] = k0B; cbufB[64 + lane] = k1B;
    MATVEC2(PA, PB);

    float nqA = k0A * k0A + k1A * k1A;    // ||mem_0||^2
    float nqB = k0B * k0B + k1B * k1B;
    #define RND2I(C) nqA = dpp_add_f<C>(nqA); nqB = dpp_add_f<C>(nqB);
    RND2I(0x111) RND2I(0x112) RND2I(0x114) RND2I(0x118) RND2I(0x142) RND2I(0x143)
    #undef RND2I
    float nsqA = lane63(nqA);
    float nsqB = lane63(nqB);
    float rnA = 1.f, rnB = 1.f;

    const float* encRow = enc + (size_t)b * 25600;
    const float* sWRow  = sWp + (size_t)b * 25600;
    const float* kgRowA = kg + (size_t)b * 5120 + mA;
    const float* kgRowB = kg + (size_t)b * 5120 + mB;

    float sw0 = sWRow[e0], sw1 = sWRow[e1];   // shared (per-b)
    float gA, gB;
    {
        const float sv0 = encRow[e0], sv1 = encRow[e1];
        const float kgA0 = kgRowA[0];
        const float kgB0 = kgRowB[0];
        float q1A = sv0 * nmA0 + sv1 * nmA1;
        float q1B = sv0 * nmB0 + sv1 * nmB1;
        #define RND2G(C) q1A = dpp_add_f<C>(q1A); q1B = dpp_add_f<C>(q1B);
        RND2G(0x111) RND2G(0x112) RND2G(0x114) RND2G(0x118) RND2G(0x142) RND2G(0x143)
        #undef RND2G
        gA = 1.f / (1.f + __expf(-(lane63(q1A) + kgA0)));   // rn == 1 at t=0
        gB = 1.f / (1.f + __expf(-(lane63(q1B) + kgB0)));
    }

    for (int step = 0; step < 256; ++step) {
        const int nxt = (step < 255 ? step + 1 : 255);
        const float nsv0 = encRow[nxt * 100 + e0], nsv1 = encRow[nxt * 100 + e1];
        const float nsw0 = sWRow[nxt * 100 + e0], nsw1 = sWRow[nxt * 100 + e1];
        const float nkgA = kgRowA[nxt * 20];
        const float nkgB = kgRowB[nxt * 20];

        // critical path (x2, independent): P -> x -> cand -> LDS matvec -> P'
        const float xA0 = rnA * PA.x + kvA0 + sw0;
        const float xA1 = rnA * PA.y + kvA1 + sw1;
        const float xB0 = rnB * PB.x + kvB0 + sw0;
        const float xB1 = rnB * PB.y + kvB1 + sw1;
        float cA0 = (xA0 >= 0.f) ? xA0 : pa * xA0;
        float cA1 = (xA1 >= 0.f) ? xA1 : pa * xA1;
        float cB0 = (xB0 >= 0.f) ? xB0 : pa * xB0;
        float cB1 = (xB1 >= 0.f) ? xB1 : pa * xB1;
        cA1 *= h; cB1 *= h;

        cbufA[lane] = cA0; cbufA[64 + lane] = cA1;   // issue stores early
        cbufB[lane] = cB0; cbufB[64 + lane] = cB1;

        // off-path norm partials (overlap LDS round-trip)
        float q3A = nmA0 * cA0 + nmA1 * cA1;         // nm . cand
        float p4A = cA0 * cA0 + cA1 * cA1;           // cand . cand
        float q3B = nmB0 * cB0 + nmB1 * cB1;
        float p4B = cB0 * cB0 + cB1 * cB1;
        #define RND4(C) q3A = dpp_add_f<C>(q3A); p4A = dpp_add_f<C>(p4A); \
                        q3B = dpp_add_f<C>(q3B); p4B = dpp_add_f<C>(p4B);
        RND4(0x111) RND4(0x112) RND4(0x114) RND4(0x118) RND4(0x142) RND4(0x143)
        #undef RND4

        v2f QA, QB;
        MATVEC2(QA, QB);

        const float Q3A = lane63(q3A);
        const float P4A = lane63(p4A);
        const float Q3B = lane63(q3B);
        const float P4B = lane63(p4B);
        const float n2A = nsqA + 2.f * (gA * rnA) * Q3A + gA * gA * P4A;
        const float n2B = nsqB + 2.f * (gB * rnB) * Q3B + gB * gB * P4B;
        const float rnnA = rsqrtf(n2A);              // rn_{t+1}
        const float rnnB = rsqrtf(n2B);
        nsqA = 1.f; nsqB = 1.f;

        nmA0 = rnA * nmA0 + gA * cA0;
        nmA1 = rnA * nmA1 + gA * cA1;
        nmB0 = rnB * nmB0 + gB * cB0;
        nmB1 = rnB * nmB1 + gB * cB1;
        PA.x = rnA * PA.x + gA * QA.x;
        PA.y = rnA * PA.y + gA * QA.y;
        PB.x = rnB * PB.x + gB * QB.x;
        PB.y = rnB * PB.y + gB * QB.y;

        // gates for step t+1 (overlap next iteration's front)
        float q1A = nsv0 * nmA0 + nsv1 * nmA1;
        float q1B = nsv0 * nmB0 + nsv1 * nmB1;
        #define RND2(C) q1A = dpp_add_f<C>(q1A); q1B = dpp_add_f<C>(q1B);
        RND2(0x111) RND2(0x112) RND2(0x114) RND2(0x118) RND2(0x142) RND2(0x143)
        #undef RND2
        gA = 1.f / (1.f + __expf(-(rnnA * lane63(q1A) + nkgA)));
        gB = 1.f / (1.f + __expf(-(rnnB * lane63(q1B) + nkgB)));

        rnA = rnnA; rnB = rnnB;
        sw0 = nsw0; sw1 = nsw1;
    }
    float* orowA = out + (size_t)(b * 20 + mA) * 100;
    float* orowB = out + (size_t)(b * 20 + mB) * 100;
    orowA[e0] = nmA0 * rnA;
    orowB[e0] = nmB0 * rnB;
    if (hi) {
        orowA[e1] = nmA1 * rnA;
        orowB[e1] = nmB1 * rnB;
    }
}

extern "C" void kernel_launch(void* const* d_in, const int* in_sizes, int n_in,
                              void* d_out, int out_size, void* d_ws, size_t ws_size,
                              hipStream_t stream) {
    const float* batch = (const float*)d_in[0];
    const float* encm  = (const float*)d_in[1];
    const float* keys  = (const float*)d_in[2];
    const float* U     = (const float*)d_in[3];
    const float* V     = (const float*)d_in[4];
    const float* W     = (const float*)d_in[5];
    const float* pa    = (const float*)d_in[6];
    float* out = (float*)d_out;

    float* enc = (float*)d_ws;          // 819200 floats
    float* sWp = enc + 819200;          // 819200 floats
    float* kgb = sWp + 819200;          // 163840 floats
    float* T   = kgb + 163840;          // 12800 floats

    encode_k<<<8192, 320, 0, stream>>>(batch, encm, enc);
    prep_k<<<100, 128, 0, stream>>>(W, keys, T);
    project_k<<<2048, 128, 0, stream>>>(enc, T, sWp, kgb);
    entnet_scan<<<320, 64, 0, stream>>>(enc, sWp, kgb, keys, U, V, pa, out);
}

// Round 3
// 530.965 us; speedup vs baseline: 1.6803x; 1.6803x over previous
//
#include <hip/hip_runtime.h>

// EntNet: B=32, S=256, L=64, D=100, M=20
// K1 encode_k : one row/block contiguous streaming -> LDS stage -> column reduce
// K0 prep_k   : T[d][e] = W[e][d] / keys
// K2 project_k: sWp = enc·W^T, kg = enc·keys^T via T
// K3 entnet_scan: 640 chains, ONE chain per 128-thread block (2 waves).
//    Thread tid owns element e=tid (100 active). U row = 50 VGPRs/lane ->
//    no AGPR/scratch pressure (round-2 lesson: 200-float U arrays go to AGPRs
//    and serialize everything). One __syncthreads per step; all 4 cross-lane
//    dots (nm·c, c·c, nsv·nm, nsv·c) reduced via DPP BEFORE the barrier,
//    gate rebuilt after the matvec as nsv·nm' = rn*(nsv·nm)+g*(nsv·c).
//    Cand + reduction slots parity double-buffered (no 2nd barrier).

typedef float v2f __attribute__((ext_vector_type(2)));

__global__ __launch_bounds__(320) void encode_k(
    const float* __restrict__ batch,
    const float* __restrict__ encm,
    float* __restrict__ enc)
{
    __shared__ float prod[6400];
    __shared__ float part[200];
    const int t = threadIdx.x;
    const int row = blockIdx.x;       // 8192 blocks
    const float4* rb = (const float4*)batch + (size_t)row * 1600;
    const float4* e4 = (const float4*)encm;
    float4* p4 = (float4*)prod;
    #pragma unroll
    for (int i = 0; i < 5; ++i) {
        const int idx = i * 320 + t;
        float4 x = rb[idx];
        float4 mu = e4[idx];
        float4 p;
        p.x = x.x * mu.x; p.y = x.y * mu.y; p.z = x.z * mu.z; p.w = x.w * mu.w;
        p4[idx] = p;
    }
    __syncthreads();
    if (t < 200) {
        const int c = (t < 100) ? t : (t - 100);
        const int l0 = (t < 100) ? 0 : 32;
        float s0 = 0.f, s1 = 0.f;
        #pragma unroll
        for (int l = 0; l < 32; l += 2) {
            s0 += prod[(l0 + l) * 100 + c];
            s1 += prod[(l0 + l + 1) * 100 + c];
        }
        part[t] = s0 + s1;
    }
    __syncthreads();
    if (t < 100) enc[(size_t)row * 100 + t] = part[t] + part[100 + t];
}

__global__ void prep_k(const float* __restrict__ W,
                       const float* __restrict__ keys,
                       float* __restrict__ T)
{
    const int d = blockIdx.x;
    const int e = threadIdx.x;
    float v = 0.f;
    if (e < 100) v = W[e * 100 + d];
    else if (e < 120) v = keys[(e - 100) * 100 + d];
    T[d * 128 + e] = v;
}

__global__ __launch_bounds__(128) void project_k(
    const float* __restrict__ enc,
    const float* __restrict__ T,
    float* __restrict__ sWp,
    float* __restrict__ kg)
{
    __shared__ float encS[400];
    const int t = threadIdx.x;
    const int row0 = blockIdx.x * 4;
    if (t < 100) ((float4*)encS)[t] = ((const float4*)(enc + (size_t)row0 * 100))[t];
    __syncthreads();
    float a0 = 0.f, a1 = 0.f, a2 = 0.f, a3 = 0.f;
    #pragma unroll 4
    for (int d = 0; d < 100; ++d) {
        const float w = T[d * 128 + t];
        a0 += w * encS[d];
        a1 += w * encS[100 + d];
        a2 += w * encS[200 + d];
        a3 += w * encS[300 + d];
    }
    if (t < 100) {
        sWp[(size_t)row0 * 100 + t]       = a0;
        sWp[(size_t)(row0 + 1) * 100 + t] = a1;
        sWp[(size_t)(row0 + 2) * 100 + t] = a2;
        sWp[(size_t)(row0 + 3) * 100 + t] = a3;
    } else if (t < 120) {
        const int m = t - 100;
        kg[(size_t)row0 * 20 + m]       = a0;
        kg[(size_t)(row0 + 1) * 20 + m] = a1;
        kg[(size_t)(row0 + 2) * 20 + m] = a2;
        kg[(size_t)(row0 + 3) * 20 + m] = a3;
    }
}

template <int CTRL>
__device__ __forceinline__ float dpp_add_f(float x) {
    int s = __builtin_amdgcn_update_dpp(0, __float_as_int(x), CTRL, 0xF, 0xF, true);
    return x + __int_as_float(s);
}
#define DPP6(v) v = dpp_add_f<0x111>(v); v = dpp_add_f<0x112>(v); v = dpp_add_f<0x114>(v); \
                v = dpp_add_f<0x118>(v); v = dpp_add_f<0x142>(v); v = dpp_add_f<0x143>(v);

// Lane-local matvec step: 4 independent accumulator chains over 25 float4
// broadcast reads of cand.
#define MATVEC(QOUT, CBPTR)                                             \
    {                                                                   \
        v2f A0 = {0.f,0.f}, A1 = {0.f,0.f};                             \
        v2f A2 = {0.f,0.f}, A3 = {0.f,0.f};                             \
        _Pragma("unroll")                                               \
        for (int j = 0; j < 25; ++j) {                                  \
            float4 cc = (CBPTR)[j];                                     \
            v2f lo = {cc.x, cc.y}, hi4 = {cc.z, cc.w};                  \
            if (j & 1) {                                                \
                A2 = __builtin_elementwise_fma(UE[2*j],   lo,  A2);     \
                A3 = __builtin_elementwise_fma(UE[2*j+1], hi4, A3);     \
            } else {                                                    \
                A0 = __builtin_elementwise_fma(UE[2*j],   lo,  A0);     \
                A1 = __builtin_elementwise_fma(UE[2*j+1], hi4, A1);     \
            }                                                           \
        }                                                               \
        v2f S = (A0 + A1) + (A2 + A3);                                  \
        QOUT = S.x + S.y;                                               \
    }

__global__ __launch_bounds__(128) void entnet_scan(
    const float* __restrict__ enc,    // [8192*100]
    const float* __restrict__ sWp,    // [8192*100]
    const float* __restrict__ kg,     // [8192*20]
    const float* __restrict__ keys,   // [20*100]
    const float* __restrict__ U,      // [100*100]
    const float* __restrict__ V,      // [100*100]
    const float* __restrict__ paPtr,
    float* __restrict__ out)          // [32*20*100]
{
    __shared__ float4 cbuf4[2][32];   // parity-double-buffered cand (128 floats)
    __shared__ float4 red[2][2];      // [parity][wave] = {q3,p4,q0,r1}
    float* cbuf = (float*)cbuf4;
    const int tid  = threadIdx.x;
    const int lane = tid & 63;
    const int wid  = tid >> 6;
    // 640 blocks: XCD = blockIdx%8 serves b in {4*xcd..4*xcd+3}
    const int xcd = blockIdx.x & 7;
    const int gg  = blockIdx.x >> 3;          // 0..79
    const int b = xcd * 4 + gg / 20;
    const int m = gg % 20;
    const bool act = (tid < 100);
    const float h = act ? 1.f : 0.f;
    const int e = act ? tid : 99;
    const float pa = paPtr[0];

    // U row e as (k,k+1) v2f pairs: 50 VGPRs.
    v2f UE[50];
    {
        const float4* u = (const float4*)(U + e * 100);
        #pragma unroll
        for (int k = 0; k < 25; ++k) {
            float4 a = u[k];
            UE[2*k]   = (v2f){a.x, a.y};
            UE[2*k+1] = (v2f){a.z, a.w};
        }
    }

    // kv = V[e,:] . keys[m,:]
    float kv = 0.f;
    {
        const float4* km = (const float4*)(keys + m * 100);
        const float4* vv = (const float4*)(V + e * 100);
        #pragma unroll
        for (int k = 0; k < 25; ++k) {
            float4 a = vv[k], kk = km[k];
            kv += a.x * kk.x + a.y * kk.y + a.z * kk.z + a.w * kk.w;
        }
    }

    const float* encRow = enc + (size_t)b * 25600;
    const float* sWRow  = sWp + (size_t)b * 25600;
    const float* kgRow  = kg + (size_t)b * 5120 + m;

    const float k0 = keys[m * 100 + e];
    float nm = k0;                    // unnormalized mem element; true mem = rn*nm

    // ---- init: P = U·nm0 (via buffer 1), nsq = ||nm0||², Q1i = enc0·nm0 ----
    cbuf[128 + tid] = k0;
    float nq  = h * k0 * k0;
    const float sv0 = encRow[e];
    float q1i = h * sv0 * k0;
    DPP6(nq) DPP6(q1i)
    if (lane == 63) red[1][wid] = (float4){nq, q1i, 0.f, 0.f};
    __syncthreads();

    float P;
    {
        const float4* cb1 = (const float4*)(&cbuf[128]);
        MATVEC(P, cb1);
    }
    float nsq, g;
    {
        float4 r0 = red[1][0], r1 = red[1][1];
        nsq = r0.x + r1.x;
        const float Q1 = r0.y + r1.y;
        g = 1.f / (1.f + __expf(-(Q1 + kgRow[0])));   // rn == 1 at t=0
    }
    float rn = 1.f;
    float sw = sWRow[e];

    for (int step = 0; step < 256; ++step) {
        const int nxt = (step < 255 ? step + 1 : 255);
        const float nsv = encRow[nxt * 100 + e];
        const float nsw = sWRow[nxt * 100 + e];
        const float nkg = kgRow[nxt * 20];

        // front: cand
        const float x = rn * P + kv + sw;
        const float c = (x >= 0.f) ? x : pa * x;
        const int bi = step & 1;
        cbuf[bi * 128 + tid] = c;     // dummy lanes write pad 100..127, never read

        // all 4 cross-lane dots BEFORE the barrier (h-masked)
        float q3  = h * nm * c;       // nm . cand
        float p4  = h * c * c;        // cand . cand
        float q0  = h * nsv * nm;     // nsv . nm
        float r1v = h * nsv * c;      // nsv . cand
        #define RND4(C) q3 = dpp_add_f<C>(q3); p4 = dpp_add_f<C>(p4); \
                        q0 = dpp_add_f<C>(q0); r1v = dpp_add_f<C>(r1v);
        RND4(0x111) RND4(0x112) RND4(0x114) RND4(0x118) RND4(0x142) RND4(0x143)
        #undef RND4
        if (lane == 63) red[bi][wid] = (float4){q3, p4, q0, r1v};
        __syncthreads();

        // matvec: 25 uniform ds_read_b128 broadcasts + 50 pk_fma
        float Q;
        {
            const float4* cb = (const float4*)(&cbuf[bi * 128]);
            MATVEC(Q, cb);
        }

        float4 ra = red[bi][0], rb = red[bi][1];
        const float Q3 = ra.x + rb.x;
        const float P4 = ra.y + rb.y;
        const float Q0 = ra.z + rb.z;
        const float R1 = ra.w + rb.w;

        const float n2  = nsq + 2.f * (g * rn) * Q3 + g * g * P4;
        const float rnn = rsqrtf(n2);             // rn_{t+1}
        nsq = 1.f;

        nm = rn * nm + g * c;
        P  = rn * P  + g * Q;

        // gate for t+1: nsv·nm' = rn*(nsv·nm) + g*(nsv·cand)
        const float Q1 = rn * Q0 + g * R1;
        g = 1.f / (1.f + __expf(-(rnn * Q1 + nkg)));

        rn = rnn;
        sw = nsw;
    }
    if (act) out[(size_t)(b * 20 + m) * 100 + tid] = nm * rn;
}

extern "C" void kernel_launch(void* const* d_in, const int* in_sizes, int n_in,
                              void* d_out, int out_size, void* d_ws, size_t ws_size,
                              hipStream_t stream) {
    const float* batch = (const float*)d_in[0];
    const float* encm  = (const float*)d_in[1];
    const float* keys  = (const float*)d_in[2];
    const float* U     = (const float*)d_in[3];
    const float* V     = (const float*)d_in[4];
    const float* W     = (const float*)d_in[5];
    const float* pa    = (const float*)d_in[6];
    float* out = (float*)d_out;

    float* enc = (float*)d_ws;          // 819200 floats
    float* sWp = enc + 819200;          // 819200 floats
    float* kgb = sWp + 819200;          // 163840 floats
    float* T   = kgb + 163840;          // 12800 floats

    encode_k<<<8192, 320, 0, stream>>>(batch, encm, enc);
    prep_k<<<100, 128, 0, stream>>>(W, keys, T);
    project_k<<<2048, 128, 0, stream>>>(enc, T, sWp, kgb);
    entnet_scan<<<640, 128, 0, stream>>>(enc, sWp, kgb, keys, U, V, pa, out);
}